// Round 13
// baseline (202.273 us; speedup 1.0000x reference)
//
#include <hip/hip_runtime.h>

#define N_NODES 50000
#define N_EDGES 1600000
#define HEADS 4
#define DPH 16
#define F_IN 128
#define HD 64   // HEADS * DPH
#define NCHAIN 16

#define EA 960000                  // edge partition A = [0, EA)
#define EB 640000                  // edge partition B = [EA, N_EDGES)

// K0: round-9 proven 1:4 mix (qkv + build-A)
#define K0_TOTAL 4166
#define K0_QKV_BLOCKS 3125         // 50000/16
#define K0_LINK_STRIDE (1041 * 256)

// K1: gather-A + build-B, 1:4 mix
#define K1_TOTAL 16667             // 12501 gather slots (12500 used) + 4166 build
#define K1_GATHER_BLOCKS 12500

#define K2_BLOCKS 12500

__device__ inline unsigned pack_bf16(float k, float v) {
    unsigned uk = __float_as_uint(k), uv = __float_as_uint(v);
    uk = (uk + 0x7FFFu + ((uk >> 16) & 1u)) >> 16;   // RNE to bf16
    uv = (uv + 0x7FFFu + ((uv >> 16) & 1u)) >> 16;
    return (uv << 16) | uk;
}

// ---------------------------------------------------------------------------
// Shared gather core: one wave, one node, walk the 16 chains of `head`,
// lane = t*4 + h. On return, acc_out is the value of OUTPUT DIM h*DPH+t
// (note: NOT dim `lane` — callers must index out[] with h*DPH+t) and z_out
// is the fully-reduced z for head h (replicated across the 16 t-lanes).
// ---------------------------------------------------------------------------
__device__ __forceinline__ void gather_core(int n, int lane,
                                            const int* __restrict__ head,
                                            const int2* __restrict__ elink,
                                            const float* __restrict__ Q,
                                            const unsigned* __restrict__ KV,
                                            float& acc_out, float& z_out) {
    const int t = lane >> 2;
    const int h = lane & 3;

    float qv[16];
    {
        const float4* qp = (const float4*)(Q + (size_t)n * HD + h * DPH);
        #pragma unroll
        for (int j = 0; j < 4; ++j) {
            const float4 f = qp[j];
            qv[4 * j + 0] = f.x; qv[4 * j + 1] = f.y;
            qv[4 * j + 2] = f.z; qv[4 * j + 3] = f.w;
        }
    }

    float acc[16];
    #pragma unroll
    for (int j = 0; j < 16; ++j) acc[j] = 0.f;
    float zacc = 0.f;

    int e = head[n * NCHAIN + t];
    while (__ballot(e >= 0)) {
        if (e >= 0) {
            const int2 l = elink[e];
            const uint4* kp = (const uint4*)(KV + (size_t)l.x * HD + h * DPH);
            const uint4 w0 = kp[0], w1 = kp[1], w2 = kp[2], w3 = kp[3];
            const unsigned kw[16] = {w0.x, w0.y, w0.z, w0.w,
                                     w1.x, w1.y, w1.z, w1.w,
                                     w2.x, w2.y, w2.z, w2.w,
                                     w3.x, w3.y, w3.z, w3.w};
            float p = 0.f;
            #pragma unroll
            for (int j = 0; j < 16; ++j)
                p = fmaf(__uint_as_float(kw[j] << 16), qv[j], p);
            p = fminf(fmaxf(p * 0.25f, -5.f), 5.f);
            const float sc = __expf(p);
            #pragma unroll
            for (int j = 0; j < 16; ++j)
                acc[j] = fmaf(sc, __uint_as_float(kw[j] & 0xFFFF0000u), acc[j]);
            zacc += sc;
            e = l.y;
        }
    }

    // Reduce-scatter over t bits (masks 32,16,8,4 -> element bits 3,2,1,0).
    {
        const bool b = (lane & 32) != 0;
        float send[8], keep[8];
        #pragma unroll
        for (int j = 0; j < 8; ++j) {
            send[j] = b ? acc[j] : acc[j + 8];
            keep[j] = b ? acc[j + 8] : acc[j];
        }
        #pragma unroll
        for (int j = 0; j < 8; ++j) acc[j] = keep[j] + __shfl_xor(send[j], 32, 64);
    }
    {
        const bool b = (lane & 16) != 0;
        float send[4], keep[4];
        #pragma unroll
        for (int j = 0; j < 4; ++j) {
            send[j] = b ? acc[j] : acc[j + 4];
            keep[j] = b ? acc[j + 4] : acc[j];
        }
        #pragma unroll
        for (int j = 0; j < 4; ++j) acc[j] = keep[j] + __shfl_xor(send[j], 16, 64);
    }
    {
        const bool b = (lane & 8) != 0;
        float send[2], keep[2];
        #pragma unroll
        for (int j = 0; j < 2; ++j) {
            send[j] = b ? acc[j] : acc[j + 2];
            keep[j] = b ? acc[j + 2] : acc[j];
        }
        #pragma unroll
        for (int j = 0; j < 2; ++j) acc[j] = keep[j] + __shfl_xor(send[j], 8, 64);
    }
    {
        const bool b = (lane & 4) != 0;
        const float send = b ? acc[0] : acc[1];
        const float keep = b ? acc[1] : acc[0];
        acc[0] = keep + __shfl_xor(send, 4, 64);
    }

    zacc += __shfl_xor(zacc, 4, 64);
    zacc += __shfl_xor(zacc, 8, 64);
    zacc += __shfl_xor(zacc, 16, 64);
    zacc += __shfl_xor(zacc, 32, 64);

    acc_out = acc[0];
    z_out = zacc;
}

// ---------------------------------------------------------------------------
// K0: qkv projection + build-A (edges [0, EA)), round-9 1:4 role mix.
// ---------------------------------------------------------------------------
__global__ void __launch_bounds__(256)
qkv_links_a(const float* __restrict__ x,
            const float* __restrict__ Wq,
            const float* __restrict__ Wk,
            const float* __restrict__ Wv,
            const int* __restrict__ src,
            const int* __restrict__ dst,
            float* __restrict__ Q,
            unsigned* __restrict__ KV,
            int* __restrict__ headA,
            int2* __restrict__ elink) {
    const int bx = blockIdx.x;
    const int tid = threadIdx.x;

    if ((bx & 3) == 3) {
        const int bid = bx >> 2;
        for (int i = bid * 256 + tid; i < EA; i += K0_LINK_STRIDE) {
            const int d = dst[i];
            const int nx = atomicExch(&headA[d * NCHAIN + (i & (NCHAIN - 1))], i);
            elink[i] = make_int2(src[i], nx);
        }
        return;
    }

    const int qb = bx - (bx >> 2);
    if (qb >= K0_QKV_BLOCKS) return;

    __shared__ float xs[16][F_IN + 4];
    __shared__ float kcol[16][68];
    __shared__ float vcol[16][68];
    const int node0 = qb * 16;

    for (int i = tid; i < 512; i += 256) {
        const int r = i >> 5, c4 = (i & 31) * 4;
        *(float4*)&xs[r][c4] = *(const float4*)&x[(size_t)(node0 + r) * F_IN + c4];
    }
    __syncthreads();

    const int m = tid >> 6;
    const int lane = tid & 63;
    const int cg = (lane & 15) * 4;
    const int ng = (lane >> 4) * 4;

    if (m < 3) {
        const float* W = (m == 0) ? Wq : (m == 1) ? Wk : Wv;
        float acc[4][4];
        #pragma unroll
        for (int i = 0; i < 4; ++i)
            #pragma unroll
            for (int j = 0; j < 4; ++j) acc[i][j] = 0.f;

        for (int k = 0; k < F_IN; k += 4) {
            const float4 xv0 = *(const float4*)&xs[ng + 0][k];
            const float4 xv1 = *(const float4*)&xs[ng + 1][k];
            const float4 xv2 = *(const float4*)&xs[ng + 2][k];
            const float4 xv3 = *(const float4*)&xs[ng + 3][k];
            const float4 w0 = *(const float4*)&W[(k + 0) * HD + cg];
            const float4 w1 = *(const float4*)&W[(k + 1) * HD + cg];
            const float4 w2 = *(const float4*)&W[(k + 2) * HD + cg];
            const float4 w3 = *(const float4*)&W[(k + 3) * HD + cg];
            #pragma unroll
            for (int i = 0; i < 4; ++i) {
                const float4 xv = (i == 0) ? xv0 : (i == 1) ? xv1 : (i == 2) ? xv2 : xv3;
                acc[i][0] += xv.x * w0.x + xv.y * w1.x + xv.z * w2.x + xv.w * w3.x;
                acc[i][1] += xv.x * w0.y + xv.y * w1.y + xv.z * w2.y + xv.w * w3.y;
                acc[i][2] += xv.x * w0.z + xv.y * w1.z + xv.z * w2.z + xv.w * w3.z;
                acc[i][3] += xv.x * w0.w + xv.y * w1.w + xv.z * w2.w + xv.w * w3.w;
            }
        }

        if (m == 0) {
            #pragma unroll
            for (int i = 0; i < 4; ++i)
                *(float4*)&Q[(size_t)(node0 + ng + i) * HD + cg] =
                    make_float4(acc[i][0], acc[i][1], acc[i][2], acc[i][3]);
        } else if (m == 1) {
            #pragma unroll
            for (int i = 0; i < 4; ++i)
                *(float4*)&kcol[ng + i][cg] =
                    make_float4(acc[i][0], acc[i][1], acc[i][2], acc[i][3]);
        } else {
            #pragma unroll
            for (int i = 0; i < 4; ++i)
                *(float4*)&vcol[ng + i][cg] =
                    make_float4(acc[i][0], acc[i][1], acc[i][2], acc[i][3]);
        }
    }
    __syncthreads();

    for (int i = tid; i < 16 * 64; i += 256) {
        const int nn = i >> 6, cc = i & 63;
        KV[(size_t)(node0 + nn) * HD + cc] = pack_bf16(kcol[nn][cc], vcol[nn][cc]);
    }
}

// ---------------------------------------------------------------------------
// K1: gather-A (partial, unnormalized) + build-B (edges [EA, N_EDGES)),
// 1:4 role mix. Partial wV stored at the CANONICAL index h*DPH+t.
// ---------------------------------------------------------------------------
__global__ void __launch_bounds__(256)
gather_a_links_b(const int* __restrict__ headA,
                 int* __restrict__ headB,
                 int2* __restrict__ elink,
                 const int* __restrict__ src,
                 const int* __restrict__ dst,
                 const float* __restrict__ Q,
                 const unsigned* __restrict__ KV,
                 float* __restrict__ outp,     // partial wV (= d_out)
                 float* __restrict__ z_part) {
    const int bx = blockIdx.x;
    const int tid = threadIdx.x;

    if ((bx & 3) == 3) {
        // ---- build-B role: one edge per thread ----
        const int gid = (bx >> 2) * 256 + tid;
        if (gid < EB) {
            const int i = EA + gid;
            const int d = dst[i];
            const int nx = atomicExch(&headB[d * NCHAIN + (i & (NCHAIN - 1))], i);
            elink[i] = make_int2(src[i], nx);
        }
        return;
    }

    const int gb = bx - (bx >> 2);
    if (gb >= K1_GATHER_BLOCKS) return;
    const int n = gb * 4 + (tid >> 6);
    if (n >= N_NODES) return;
    const int lane = tid & 63;
    const int od = (lane & 3) * DPH + (lane >> 2);   // canonical out dim

    float a, z;
    gather_core(n, lane, headA, elink, Q, KV, a, z);
    outp[(size_t)n * HD + od] = a;            // raw partial, no normalize
    if (lane < 4) z_part[n * 4 + lane] = z;   // lanes 0-3 are t=0, h=0..3
}

// ---------------------------------------------------------------------------
// K2: gather-B + combine partials + normalize -> final d_out (canonical idx).
// ---------------------------------------------------------------------------
__global__ void __launch_bounds__(256)
gather_b_final(const int* __restrict__ headB,
               const int2* __restrict__ elink,
               const float* __restrict__ Q,
               const unsigned* __restrict__ KV,
               const float* __restrict__ z_part,
               float* __restrict__ out) {
    const int n = blockIdx.x * 4 + (threadIdx.x >> 6);
    if (n >= N_NODES) return;
    const int lane = threadIdx.x & 63;
    const int od = (lane & 3) * DPH + (lane >> 2);   // canonical out dim

    float a, z;
    gather_core(n, lane, headB, elink, Q, KV, a, z);

    const float prev = out[(size_t)n * HD + od];
    const float zA = z_part[n * 4 + (lane & 3)];
    out[(size_t)n * HD + od] = (prev + a) / (zA + z + 1e-6f);
}

extern "C" void kernel_launch(void* const* d_in, const int* in_sizes, int n_in,
                              void* d_out, int out_size, void* d_ws, size_t ws_size,
                              hipStream_t stream) {
    const float* x   = (const float*)d_in[0];
    const int*   src = (const int*)d_in[1];
    const int*   dst = (const int*)d_in[2];
    const float* Wq  = (const float*)d_in[3];
    const float* Wk  = (const float*)d_in[4];
    const float* Wv  = (const float*)d_in[5];
    float* out = (float*)d_out;

    float*    Q      = (float*)d_ws;                           // 12.8 MB
    unsigned* KV     = (unsigned*)(Q + (size_t)N_NODES * HD);  // 12.8 MB
    int2*     elink  = (int2*)(KV + (size_t)N_NODES * HD);     // 12.8 MB
    int*      headA  = (int*)(elink + (size_t)N_EDGES);        // 3.2 MB
    int*      headB  = headA + (size_t)N_NODES * NCHAIN;       // 3.2 MB
    float*    z_part = (float*)(headB + (size_t)N_NODES * NCHAIN); // 0.8 MB

    hipMemsetAsync(headA, 0xFF, (size_t)N_NODES * NCHAIN * sizeof(int), stream);
    hipMemsetAsync(headB, 0xFF, (size_t)N_NODES * NCHAIN * sizeof(int), stream);

    qkv_links_a<<<K0_TOTAL, 256, 0, stream>>>(x, Wq, Wk, Wv, src, dst,
                                              Q, KV, headA, elink);
    gather_a_links_b<<<K1_TOTAL, 256, 0, stream>>>(headA, headB, elink, src, dst,
                                                   Q, KV, out, z_part);
    gather_b_final<<<K2_BLOCKS, 256, 0, stream>>>(headB, elink, Q, KV, z_part, out);
}

// Round 14
// 161.665 us; speedup vs baseline: 1.2512x; 1.2512x over previous
//
#include <hip/hip_runtime.h>

#define N_NODES 50000
#define N_EDGES 1600000
#define HEADS 4
#define DPH 16
#define F_IN 128
#define HD 64   // HEADS * DPH
#define NCHAIN 16

#define QKV_BLOCKS 3125            // 50000/16 exact
#define TOTAL_BLOCKS 4166          // 3125 qkv + 1041 link, 1:4 interleave
#define LINK_STRIDE (1041 * 256)

using bf16x8 = __attribute__((ext_vector_type(8))) short;
using f32x4  = __attribute__((ext_vector_type(4))) float;

__device__ inline unsigned short bf16_rne(float f) {
    const unsigned u = __float_as_uint(f);
    return (unsigned short)((u + 0x7FFFu + ((u >> 16) & 1u)) >> 16);
}
__device__ inline unsigned pack_kv(float k, float v) {
    return ((unsigned)bf16_rne(v) << 16) | (unsigned)bf16_rne(k);
}

// ---------------------------------------------------------------------------
// Repack W into MFMA B-fragment order (bf16). Frag f = (mat*4+cb)*4+kg:
// lane holds 8 bf16, elem j = W_mat[kg*32 + (lane>>4)*8 + j][cb*16 + (lane&15)].
// Same per-lane k-slot mapping as the A-frags built from x, so the pairing is
// self-consistent; C layout per m89 (col=lane&15, row=(lane>>4)*4+reg).
// ---------------------------------------------------------------------------
__global__ void repack_w(const float* __restrict__ Wq,
                         const float* __restrict__ Wk,
                         const float* __restrict__ Wv,
                         uint4* __restrict__ Wpk) {
    const int tile = blockIdx.x;          // 0..11 = mat*4 + cb
    const int mat = tile >> 2, cb = tile & 3;
    const float* W = (mat == 0) ? Wq : (mat == 1) ? Wk : Wv;
    const int tid = threadIdx.x;          // 256 = 4 kg x 64 lane
    const int kg = tid >> 6, lane = tid & 63;
    const int kbase = kg * 32 + (lane >> 4) * 8;
    const int c = cb * 16 + (lane & 15);
    unsigned w[4];
    #pragma unroll
    for (int p = 0; p < 4; ++p) {
        const unsigned lo = bf16_rne(W[(kbase + 2 * p) * HD + c]);
        const unsigned hi = bf16_rne(W[(kbase + 2 * p + 1) * HD + c]);
        w[p] = (hi << 16) | lo;
    }
    Wpk[(tile * 4 + kg) * 64 + lane] = make_uint4(w[0], w[1], w[2], w[3]);
}

// ---------------------------------------------------------------------------
// Fused kernel, round-9 1:4 role mix. qkv role now uses MFMA: 16 nodes per
// block, wave w computes col-block w of Q, K and V (12 MFMAs/wave), packs
// K/V to interleaved bf16 in-register. link role: 16 chains/node, ONE
// atomicExch per edge (~19G line-req/s atomic-unit floor) — now the long pole.
// ---------------------------------------------------------------------------
__global__ void __launch_bounds__(256)
qkv_and_links(const float* __restrict__ x,
              const uint4* __restrict__ Wpk,
              const int* __restrict__ src,
              const int* __restrict__ dst,
              float* __restrict__ Q,
              unsigned* __restrict__ KV,
              int* __restrict__ head,
              int2* __restrict__ elink) {
    const int bx = blockIdx.x;
    const int tid = threadIdx.x;

    if ((bx & 3) == 3) {
        // ---- link-build role ----
        const int bid = bx >> 2;
        for (int i = bid * 256 + tid; i < N_EDGES; i += LINK_STRIDE) {
            const int d = dst[i];
            const int nx = atomicExch(&head[d * NCHAIN + (i & (NCHAIN - 1))], i);
            elink[i] = make_int2(src[i], nx);
        }
        return;
    }

    // ---- qkv role (MFMA) ----
    const int qb = bx - (bx >> 2);       // 0..3124
    const int node0 = qb * 16;

    __shared__ float xs[16][132];        // 132: 16B-aligned rows, bank-spread
    for (int i = tid; i < 512; i += 256) {          // 512 float4 = 16 x 32
        const int r = i >> 5, c4 = (i & 31) * 4;
        *(float4*)&xs[r][c4] = *(const float4*)&x[(size_t)(node0 + r) * F_IN + c4];
    }
    __syncthreads();

    const int w = tid >> 6;              // wave = col block cb (0..3)
    const int lane = tid & 63;
    const int row = lane & 15;           // A row (node within tile)
    const int kb = (lane >> 4) * 8;      // k-slot base within k-group

    // A fragments: x rows -> bf16, one frag per 32-wide k-group
    bf16x8 a[4];
    #pragma unroll
    for (int kg = 0; kg < 4; ++kg) {
        const float4 fa = *(const float4*)&xs[row][kg * 32 + kb];
        const float4 fb = *(const float4*)&xs[row][kg * 32 + kb + 4];
        a[kg][0] = (short)bf16_rne(fa.x); a[kg][1] = (short)bf16_rne(fa.y);
        a[kg][2] = (short)bf16_rne(fa.z); a[kg][3] = (short)bf16_rne(fa.w);
        a[kg][4] = (short)bf16_rne(fb.x); a[kg][5] = (short)bf16_rne(fb.y);
        a[kg][6] = (short)bf16_rne(fb.z); a[kg][7] = (short)bf16_rne(fb.w);
    }

    const bf16x8* Wp = (const bf16x8*)Wpk;
    f32x4 accQ = {0.f, 0.f, 0.f, 0.f};
    f32x4 accK = {0.f, 0.f, 0.f, 0.f};
    f32x4 accV = {0.f, 0.f, 0.f, 0.f};
    #pragma unroll
    for (int kg = 0; kg < 4; ++kg) {
        accQ = __builtin_amdgcn_mfma_f32_16x16x32_bf16(
            a[kg], Wp[((0 * 4 + w) * 4 + kg) * 64 + lane], accQ, 0, 0, 0);
        accK = __builtin_amdgcn_mfma_f32_16x16x32_bf16(
            a[kg], Wp[((1 * 4 + w) * 4 + kg) * 64 + lane], accK, 0, 0, 0);
        accV = __builtin_amdgcn_mfma_f32_16x16x32_bf16(
            a[kg], Wp[((2 * 4 + w) * 4 + kg) * 64 + lane], accV, 0, 0, 0);
    }

    // epilogue: C col = lane&15, row = (lane>>4)*4 + reg  (m89-verified)
    const int crow0 = (lane >> 4) * 4;
    const int ccol = w * 16 + (lane & 15);
    #pragma unroll
    for (int r = 0; r < 4; ++r) {
        const int n = node0 + crow0 + r;
        Q[(size_t)n * HD + ccol] = accQ[r];
        KV[(size_t)n * HD + ccol] = pack_kv(accK[r], accV[r]);
    }
}

// ---------------------------------------------------------------------------
// Gather (unchanged, round-9 proven): one wave per node, lane = t*4+h, 16
// chains walked in parallel, lane-local hot loop, reduce-scatter epilogue.
// ---------------------------------------------------------------------------
__global__ void gather_chains(const int* __restrict__ head,
                              const int2* __restrict__ elink,
                              const float* __restrict__ Q,
                              const unsigned* __restrict__ KV,
                              float* __restrict__ out) {
    const int n = blockIdx.x * 4 + (threadIdx.x >> 6);
    if (n >= N_NODES) return;
    const int lane = threadIdx.x & 63;
    const int t = lane >> 2;   // chain slot 0..15
    const int h = lane & 3;    // head

    float qv[16];
    {
        const float4* qp = (const float4*)(Q + (size_t)n * HD + h * DPH);
        #pragma unroll
        for (int j = 0; j < 4; ++j) {
            const float4 f = qp[j];
            qv[4 * j + 0] = f.x; qv[4 * j + 1] = f.y;
            qv[4 * j + 2] = f.z; qv[4 * j + 3] = f.w;
        }
    }

    float acc[16];
    #pragma unroll
    for (int j = 0; j < 16; ++j) acc[j] = 0.f;
    float zacc = 0.f;

    int e = head[n * NCHAIN + t];
    while (__ballot(e >= 0)) {
        if (e >= 0) {
            const int2 l = elink[e];
            const uint4* kp = (const uint4*)(KV + (size_t)l.x * HD + h * DPH);
            const uint4 w0 = kp[0], w1 = kp[1], w2 = kp[2], w3 = kp[3];
            const unsigned kw[16] = {w0.x, w0.y, w0.z, w0.w,
                                     w1.x, w1.y, w1.z, w1.w,
                                     w2.x, w2.y, w2.z, w2.w,
                                     w3.x, w3.y, w3.z, w3.w};
            float p = 0.f;
            #pragma unroll
            for (int j = 0; j < 16; ++j)
                p = fmaf(__uint_as_float(kw[j] << 16), qv[j], p);
            p = fminf(fmaxf(p * 0.25f, -5.f), 5.f);
            const float sc = __expf(p);
            #pragma unroll
            for (int j = 0; j < 16; ++j)
                acc[j] = fmaf(sc, __uint_as_float(kw[j] & 0xFFFF0000u), acc[j]);
            zacc += sc;
            e = l.y;
        }
    }

    // Reduce-scatter over t bits (masks 32,16,8,4 -> element bits 3,2,1,0).
    {
        const bool b = (lane & 32) != 0;
        float send[8], keep[8];
        #pragma unroll
        for (int j = 0; j < 8; ++j) {
            send[j] = b ? acc[j] : acc[j + 8];
            keep[j] = b ? acc[j + 8] : acc[j];
        }
        #pragma unroll
        for (int j = 0; j < 8; ++j) acc[j] = keep[j] + __shfl_xor(send[j], 32, 64);
    }
    {
        const bool b = (lane & 16) != 0;
        float send[4], keep[4];
        #pragma unroll
        for (int j = 0; j < 4; ++j) {
            send[j] = b ? acc[j] : acc[j + 4];
            keep[j] = b ? acc[j + 4] : acc[j];
        }
        #pragma unroll
        for (int j = 0; j < 4; ++j) acc[j] = keep[j] + __shfl_xor(send[j], 16, 64);
    }
    {
        const bool b = (lane & 8) != 0;
        float send[2], keep[2];
        #pragma unroll
        for (int j = 0; j < 2; ++j) {
            send[j] = b ? acc[j] : acc[j + 2];
            keep[j] = b ? acc[j + 2] : acc[j];
        }
        #pragma unroll
        for (int j = 0; j < 2; ++j) acc[j] = keep[j] + __shfl_xor(send[j], 8, 64);
    }
    {
        const bool b = (lane & 4) != 0;
        const float send = b ? acc[0] : acc[1];
        const float keep = b ? acc[1] : acc[0];
        acc[0] = keep + __shfl_xor(send, 4, 64);
    }

    // z: butterfly over the 16 t-lanes (h bits untouched)
    zacc += __shfl_xor(zacc, 4, 64);
    zacc += __shfl_xor(zacc, 8, 64);
    zacc += __shfl_xor(zacc, 16, 64);
    zacc += __shfl_xor(zacc, 32, 64);

    out[(size_t)n * HD + h * DPH + t] = acc[0] / (zacc + 1e-6f);
}

extern "C" void kernel_launch(void* const* d_in, const int* in_sizes, int n_in,
                              void* d_out, int out_size, void* d_ws, size_t ws_size,
                              hipStream_t stream) {
    const float* x   = (const float*)d_in[0];
    const int*   src = (const int*)d_in[1];
    const int*   dst = (const int*)d_in[2];
    const float* Wq  = (const float*)d_in[3];
    const float* Wk  = (const float*)d_in[4];
    const float* Wv  = (const float*)d_in[5];
    float* out = (float*)d_out;

    float*    Q     = (float*)d_ws;                          // 12.8 MB
    unsigned* KV    = (unsigned*)(Q + (size_t)N_NODES * HD); // 12.8 MB
    int2*     elink = (int2*)(KV + (size_t)N_NODES * HD);    // 12.8 MB
    int*      head  = (int*)(elink + (size_t)N_EDGES);       // 3.2 MB
    uint4*    Wpk   = (uint4*)(head + (size_t)N_NODES * NCHAIN); // 48 KB

    hipMemsetAsync(head, 0xFF, (size_t)N_NODES * NCHAIN * sizeof(int), stream);

    repack_w<<<12, 256, 0, stream>>>(Wq, Wk, Wv, Wpk);
    qkv_and_links<<<TOTAL_BLOCKS, 256, 0, stream>>>(x, Wpk, src, dst,
                                                    Q, KV, head, elink);
    gather_chains<<<(N_NODES + 3) / 4, 256, 0, stream>>>(head, elink, Q, KV, out);
}

// Round 15
// 114.901 us; speedup vs baseline: 1.7604x; 1.4070x over previous
//
#include <hip/hip_runtime.h>

#define N_NODES 50000
#define N_EDGES 1600000
#define HEADS 4
#define DPH 16
#define F_IN 128
#define HD 64   // HEADS * DPH

#define NB 196            // buckets: b = dst >> 8  (49999>>8 = 195)
#define PB 256            // partition blocks
#define EPP 6250          // edges per partition block (256*6250 = 1.6M exact)
#define SLAB_CAP 72       // mean 32 + 7 sigma

#define QKV_BLOCKS 3125   // 50000/16
#define FUSED_TOTAL 3385  // qkv blocks + partition slots (bx%13==12)

using bf16x8 = __attribute__((ext_vector_type(8))) short;
using f32x4  = __attribute__((ext_vector_type(4))) float;

__device__ inline unsigned short bf16_rne(float f) {
    const unsigned u = __float_as_uint(f);
    return (unsigned short)((u + 0x7FFFu + ((u >> 16) & 1u)) >> 16);
}
__device__ inline unsigned pack_kv(float k, float v) {
    return ((unsigned)bf16_rne(v) << 16) | (unsigned)bf16_rne(k);
}

// ---------------------------------------------------------------------------
// Repack W into MFMA B-fragment order (round-14 proven).
// ---------------------------------------------------------------------------
__global__ void repack_w(const float* __restrict__ Wq,
                         const float* __restrict__ Wk,
                         const float* __restrict__ Wv,
                         uint4* __restrict__ Wpk) {
    const int tile = blockIdx.x;          // 0..11 = mat*4 + cb
    const int mat = tile >> 2, cb = tile & 3;
    const float* W = (mat == 0) ? Wq : (mat == 1) ? Wk : Wv;
    const int tid = threadIdx.x;          // 256 = 4 kg x 64 lane
    const int kg = tid >> 6, lane = tid & 63;
    const int kbase = kg * 32 + (lane >> 4) * 8;
    const int c = cb * 16 + (lane & 15);
    unsigned w[4];
    #pragma unroll
    for (int p = 0; p < 4; ++p) {
        const unsigned lo = bf16_rne(W[(kbase + 2 * p) * HD + c]);
        const unsigned hi = bf16_rne(W[(kbase + 2 * p + 1) * HD + c]);
        w[p] = (hi << 16) | lo;
    }
    Wpk[(tile * 4 + kg) * 64 + lane] = make_uint4(w[0], w[1], w[2], w[3]);
}

// ---------------------------------------------------------------------------
// Fused: qkv-MFMA role (round-14 proven) || radix-partition role.
// Partition: 256 blocks x 6250 contiguous edges; bin by dst>>8 into private
// slab chunks with LDS counters only. Global atomics: 196 ghist adds/block
// (50K total, ~0 cost) vs round-14's 1.6M atomicExch (86 us).
// ---------------------------------------------------------------------------
__global__ void __launch_bounds__(256)
qkv_and_partition(const float* __restrict__ x,
                  const uint4* __restrict__ Wpk,
                  const int* __restrict__ src,
                  const int* __restrict__ dst,
                  float* __restrict__ Q,
                  unsigned* __restrict__ KV,
                  unsigned* __restrict__ slab,
                  int* __restrict__ gcnt,
                  int* __restrict__ ghist) {
    const int bx = blockIdx.x;
    const int tid = threadIdx.x;

    __shared__ float xs[16][132];
    __shared__ int cnt[NB];

    if ((bx % 13) == 12) {
        // ---- partition role ----
        const int pid = bx / 13;
        if (pid >= PB) return;
        if (tid < NB) cnt[tid] = 0;
        __syncthreads();
        const int lo = pid * EPP, hi = lo + EPP;
        for (int i = lo + tid; i < hi; i += 256) {
            const int s = src[i], d = dst[i];
            const int b = d >> 8;
            const int c = atomicAdd(&cnt[b], 1);      // LDS atomic
            if (c < SLAB_CAP)
                slab[((size_t)b * PB + pid) * SLAB_CAP + c] =
                    ((unsigned)s << 8) | (unsigned)(d & 255);
        }
        __syncthreads();
        if (tid < NB) {
            const int c = min(cnt[tid], SLAB_CAP);
            gcnt[tid * PB + pid] = c;
            atomicAdd(&ghist[tid], c);
        }
        return;
    }

    // ---- qkv role (MFMA, round-14 verbatim) ----
    const int qb = bx - bx / 13;         // dense id: skips all %13==12 slots
    const int node0 = qb * 16;

    for (int i = tid; i < 512; i += 256) {          // 512 float4 = 16 x 32
        const int r = i >> 5, c4 = (i & 31) * 4;
        *(float4*)&xs[r][c4] = *(const float4*)&x[(size_t)(node0 + r) * F_IN + c4];
    }
    __syncthreads();

    const int w = tid >> 6;              // wave = col block (0..3)
    const int lane = tid & 63;
    const int row = lane & 15;
    const int kb = (lane >> 4) * 8;

    bf16x8 a[4];
    #pragma unroll
    for (int kg = 0; kg < 4; ++kg) {
        const float4 fa = *(const float4*)&xs[row][kg * 32 + kb];
        const float4 fb = *(const float4*)&xs[row][kg * 32 + kb + 4];
        a[kg][0] = (short)bf16_rne(fa.x); a[kg][1] = (short)bf16_rne(fa.y);
        a[kg][2] = (short)bf16_rne(fa.z); a[kg][3] = (short)bf16_rne(fa.w);
        a[kg][4] = (short)bf16_rne(fb.x); a[kg][5] = (short)bf16_rne(fb.y);
        a[kg][6] = (short)bf16_rne(fb.z); a[kg][7] = (short)bf16_rne(fb.w);
    }

    const bf16x8* Wp = (const bf16x8*)Wpk;
    f32x4 accQ = {0.f, 0.f, 0.f, 0.f};
    f32x4 accK = {0.f, 0.f, 0.f, 0.f};
    f32x4 accV = {0.f, 0.f, 0.f, 0.f};
    #pragma unroll
    for (int kg = 0; kg < 4; ++kg) {
        accQ = __builtin_amdgcn_mfma_f32_16x16x32_bf16(
            a[kg], Wp[((0 * 4 + w) * 4 + kg) * 64 + lane], accQ, 0, 0, 0);
        accK = __builtin_amdgcn_mfma_f32_16x16x32_bf16(
            a[kg], Wp[((1 * 4 + w) * 4 + kg) * 64 + lane], accK, 0, 0, 0);
        accV = __builtin_amdgcn_mfma_f32_16x16x32_bf16(
            a[kg], Wp[((2 * 4 + w) * 4 + kg) * 64 + lane], accV, 0, 0, 0);
    }

    const int crow0 = (lane >> 4) * 4;
    const int ccol = w * 16 + (lane & 15);
    #pragma unroll
    for (int r = 0; r < 4; ++r) {
        const int n = node0 + crow0 + r;
        Q[(size_t)n * HD + ccol] = accQ[r];
        KV[(size_t)n * HD + ccol] = pack_kv(accK[r], accV[r]);
    }
}

// ---------------------------------------------------------------------------
// bucket_csr: one block per bucket. deg-count (LDS atomics) -> 256-wide
// block scan -> write off[] -> place src into the bucket's contiguous esrc
// region. Each block owns its region exclusively (no cross-XCD write amp).
// ---------------------------------------------------------------------------
__global__ void __launch_bounds__(256)
bucket_csr(const unsigned* __restrict__ slab,
           const int* __restrict__ gcnt,
           const int* __restrict__ ghist,
           int* __restrict__ off,
           int* __restrict__ esrc) {
    const int b = blockIdx.x;
    const int tid = threadIdx.x;
    __shared__ int hist_s[NB];
    __shared__ int deg[256], excl[256], cursor[256];
    __shared__ int wsum[4];
    __shared__ int base_s;

    if (tid < NB) hist_s[tid] = ghist[tid];
    deg[tid] = 0;
    __syncthreads();
    if (tid == 0) {
        int s = 0;
        for (int i = 0; i < b; ++i) s += hist_s[i];
        base_s = s;
    }

    const int myc = gcnt[b * PB + tid];
    const unsigned* myslab = slab + ((size_t)b * PB + tid) * SLAB_CAP;

    // pass 1: degree histogram
    for (int c = 0; c < myc; ++c) atomicAdd(&deg[(int)(myslab[c] & 255u)], 1);
    __syncthreads();

    // 256-wide exclusive scan (4 waves, round-5 pattern)
    const int lane = tid & 63, wv = tid >> 6;
    const int v = deg[tid];
    int incl = v;
    #pragma unroll
    for (int s = 1; s < 64; s <<= 1) {
        const int t = __shfl_up(incl, s, 64);
        if (lane >= s) incl += t;
    }
    if (lane == 63) wsum[wv] = incl;
    __syncthreads();
    if (tid == 0) {
        int a = 0;
        #pragma unroll
        for (int i = 0; i < 4; ++i) { const int t = wsum[i]; wsum[i] = a; a += t; }
    }
    __syncthreads();
    const int ex = wsum[wv] + incl - v;
    excl[tid] = ex;
    cursor[tid] = ex;

    const int base = base_s;
    const int n = b * 256 + tid;
    if (n <= N_NODES) off[n] = base + ex;   // off[50000] written by b=195,tid=80
    __syncthreads();

    // pass 2: place
    for (int c = 0; c < myc; ++c) {
        const unsigned r = myslab[c];
        const int pos = atomicAdd(&cursor[(int)(r & 255u)], 1);
        esrc[base + pos] = (int)(r >> 8);
    }
}

// ---------------------------------------------------------------------------
// Gather (round-6 proven CSR form): one wave per node, lane = t*4+h, 16
// edge slots batched from consecutive esrc, lane-local hot loop,
// reduce-scatter epilogue. No elink reads (saves ~100 MB of random traffic).
// ---------------------------------------------------------------------------
__global__ void gather_csr(const int* __restrict__ off,
                           const int* __restrict__ esrc,
                           const float* __restrict__ Q,
                           const unsigned* __restrict__ KV,
                           float* __restrict__ out) {
    const int n = blockIdx.x * 4 + (threadIdx.x >> 6);
    if (n >= N_NODES) return;
    const int lane = threadIdx.x & 63;
    const int t = lane >> 2;
    const int h = lane & 3;
    const int beg = off[n];
    const int end = off[n + 1];

    float qv[16];
    {
        const float4* qp = (const float4*)(Q + (size_t)n * HD + h * DPH);
        #pragma unroll
        for (int j = 0; j < 4; ++j) {
            const float4 f = qp[j];
            qv[4 * j + 0] = f.x; qv[4 * j + 1] = f.y;
            qv[4 * j + 2] = f.z; qv[4 * j + 3] = f.w;
        }
    }

    float acc[16];
    #pragma unroll
    for (int j = 0; j < 16; ++j) acc[j] = 0.f;
    float zacc = 0.f;

    for (int base = beg; base < end; base += 16) {
        const int idx = base + t;
        const bool valid = idx < end;
        const int s = esrc[valid ? idx : end - 1];
        const uint4* kp = (const uint4*)(KV + (size_t)s * HD + h * DPH);
        const uint4 w0 = kp[0], w1 = kp[1], w2 = kp[2], w3 = kp[3];
        const unsigned kw[16] = {w0.x, w0.y, w0.z, w0.w,
                                 w1.x, w1.y, w1.z, w1.w,
                                 w2.x, w2.y, w2.z, w2.w,
                                 w3.x, w3.y, w3.z, w3.w};
        float p = 0.f;
        #pragma unroll
        for (int j = 0; j < 16; ++j)
            p = fmaf(__uint_as_float(kw[j] << 16), qv[j], p);
        p = fminf(fmaxf(p * 0.25f, -5.f), 5.f);
        float sc = __expf(p);
        sc = valid ? sc : 0.f;
        #pragma unroll
        for (int j = 0; j < 16; ++j)
            acc[j] = fmaf(sc, __uint_as_float(kw[j] & 0xFFFF0000u), acc[j]);
        zacc += sc;
    }

    // Reduce-scatter over t bits (masks 32,16,8,4 -> element bits 3,2,1,0).
    {
        const bool b = (lane & 32) != 0;
        float send[8], keep[8];
        #pragma unroll
        for (int j = 0; j < 8; ++j) {
            send[j] = b ? acc[j] : acc[j + 8];
            keep[j] = b ? acc[j + 8] : acc[j];
        }
        #pragma unroll
        for (int j = 0; j < 8; ++j) acc[j] = keep[j] + __shfl_xor(send[j], 32, 64);
    }
    {
        const bool b = (lane & 16) != 0;
        float send[4], keep[4];
        #pragma unroll
        for (int j = 0; j < 4; ++j) {
            send[j] = b ? acc[j] : acc[j + 4];
            keep[j] = b ? acc[j + 4] : acc[j];
        }
        #pragma unroll
        for (int j = 0; j < 4; ++j) acc[j] = keep[j] + __shfl_xor(send[j], 16, 64);
    }
    {
        const bool b = (lane & 8) != 0;
        float send[2], keep[2];
        #pragma unroll
        for (int j = 0; j < 2; ++j) {
            send[j] = b ? acc[j] : acc[j + 2];
            keep[j] = b ? acc[j + 2] : acc[j];
        }
        #pragma unroll
        for (int j = 0; j < 2; ++j) acc[j] = keep[j] + __shfl_xor(send[j], 8, 64);
    }
    {
        const bool b = (lane & 4) != 0;
        const float send = b ? acc[0] : acc[1];
        const float keep = b ? acc[1] : acc[0];
        acc[0] = keep + __shfl_xor(send, 4, 64);
    }

    zacc += __shfl_xor(zacc, 4, 64);
    zacc += __shfl_xor(zacc, 8, 64);
    zacc += __shfl_xor(zacc, 16, 64);
    zacc += __shfl_xor(zacc, 32, 64);

    out[(size_t)n * HD + h * DPH + t] = acc[0] / (zacc + 1e-6f);
}

extern "C" void kernel_launch(void* const* d_in, const int* in_sizes, int n_in,
                              void* d_out, int out_size, void* d_ws, size_t ws_size,
                              hipStream_t stream) {
    const float* x   = (const float*)d_in[0];
    const int*   src = (const int*)d_in[1];
    const int*   dst = (const int*)d_in[2];
    const float* Wq  = (const float*)d_in[3];
    const float* Wk  = (const float*)d_in[4];
    const float* Wv  = (const float*)d_in[5];
    float* out = (float*)d_out;

    float*    Q     = (float*)d_ws;                            // 12.8 MB
    unsigned* KV    = (unsigned*)(Q + (size_t)N_NODES * HD);   // 12.8 MB
    uint4*    Wpk   = (uint4*)(KV + (size_t)N_NODES * HD);     // 48 KB
    unsigned* slab  = (unsigned*)(Wpk + 12 * 4 * 64);          // 14.45 MB
    int*      gcnt  = (int*)(slab + (size_t)NB * PB * SLAB_CAP); // 200 KB
    int*      ghist = gcnt + NB * PB;                          // 784 B
    int*      off   = ghist + NB;                              // 200 KB
    int*      esrc  = off + (N_NODES + 1);                     // 6.4 MB

    hipMemsetAsync(ghist, 0, NB * sizeof(int), stream);

    repack_w<<<12, 256, 0, stream>>>(Wq, Wk, Wv, Wpk);
    qkv_and_partition<<<FUSED_TOTAL, 256, 0, stream>>>(x, Wpk, src, dst,
                                                       Q, KV, slab, gcnt, ghist);
    bucket_csr<<<NB, 256, 0, stream>>>(slab, gcnt, ghist, off, esrc);
    gather_csr<<<(N_NODES + 3) / 4, 256, 0, stream>>>(off, esrc, Q, KV, out);
}

// Round 16
// 106.901 us; speedup vs baseline: 1.8922x; 1.0748x over previous
//
#include <hip/hip_runtime.h>

#define N_NODES 50000
#define N_EDGES 1600000
#define HEADS 4
#define DPH 16
#define F_IN 128
#define HD 64   // HEADS * DPH

#define NB 196            // buckets: b = dst >> 8  (49999>>8 = 195)
#define PB 256            // partition blocks
#define EPP 6250          // edges per partition block (256*6250 = 1.6M exact)
#define SLAB_CAP 72       // mean 32 + 7 sigma
#define TILE 2048

#define QKV_BLOCKS 3125   // 50000/16
#define FUSED_TOTAL 3385  // qkv blocks + partition slots (bx%13==12)

using bf16x8 = __attribute__((ext_vector_type(8))) short;
using f32x4  = __attribute__((ext_vector_type(4))) float;

__device__ inline unsigned short bf16_rne(float f) {
    const unsigned u = __float_as_uint(f);
    return (unsigned short)((u + 0x7FFFu + ((u >> 16) & 1u)) >> 16);
}
__device__ inline unsigned pack_kv(float k, float v) {
    return ((unsigned)bf16_rne(v) << 16) | (unsigned)bf16_rne(k);
}

// ---------------------------------------------------------------------------
// Repack W into MFMA B-fragment order (round-14 proven).
// ---------------------------------------------------------------------------
__global__ void repack_w(const float* __restrict__ Wq,
                         const float* __restrict__ Wk,
                         const float* __restrict__ Wv,
                         uint4* __restrict__ Wpk) {
    const int tile = blockIdx.x;          // 0..11 = mat*4 + cb
    const int mat = tile >> 2, cb = tile & 3;
    const float* W = (mat == 0) ? Wq : (mat == 1) ? Wk : Wv;
    const int tid = threadIdx.x;          // 256 = 4 kg x 64 lane
    const int kg = tid >> 6, lane = tid & 63;
    const int kbase = kg * 32 + (lane >> 4) * 8;
    const int c = cb * 16 + (lane & 15);
    unsigned w[4];
    #pragma unroll
    for (int p = 0; p < 4; ++p) {
        const unsigned lo = bf16_rne(W[(kbase + 2 * p) * HD + c]);
        const unsigned hi = bf16_rne(W[(kbase + 2 * p + 1) * HD + c]);
        w[p] = (hi << 16) | lo;
    }
    Wpk[(tile * 4 + kg) * 64 + lane] = make_uint4(w[0], w[1], w[2], w[3]);
}

// ---------------------------------------------------------------------------
// Fused: qkv-MFMA role || radix-partition role with in-LDS tile reorder.
// Partition per 2048-edge tile: LDS-atomic rank -> 256-scan -> LDS scatter
// in bucket order -> LINEAR copy-out (runs of ~10 records hit consecutive
// slab addresses => ~8 line-touches per wave-store vs ~50 for the naive
// per-edge scatter, which was ~60us by the ~19G line-req/s law).
// ---------------------------------------------------------------------------
__global__ void __launch_bounds__(256)
qkv_and_partition(const float* __restrict__ x,
                  const uint4* __restrict__ Wpk,
                  const int* __restrict__ src,
                  const int* __restrict__ dst,
                  float* __restrict__ Q,
                  unsigned* __restrict__ KV,
                  unsigned* __restrict__ slab,
                  int* __restrict__ gcnt,
                  int* __restrict__ ghist) {
    const int bx = blockIdx.x;
    const int tid = threadIdx.x;

    __shared__ union {
        float xs[16][132];                       // qkv role (8448 B)
        struct {                                 // partition role (~13.3 KB)
            unsigned sbuf[TILE];
            unsigned char bp[TILE];
            int cnt[256];
            int toff[256];
            int gcur[256];
            int wsum[4];
        } p;
    } sm;

    if ((bx % 13) == 12) {
        // ---- partition role ----
        const int pid = bx / 13;
        if (pid >= PB) return;
        sm.p.gcur[tid] = 0;
        __syncthreads();

        const int lo = pid * EPP;
        for (int tb = 0; tb < EPP; tb += TILE) {
            const int tcnt = min(TILE, EPP - tb);
            sm.p.cnt[tid] = 0;
            __syncthreads();

            // load + rank (regs)
            unsigned rec[8]; int bb[8], rk[8];
            #pragma unroll
            for (int j = 0; j < 8; ++j) {
                const int ol = tid + j * 256;
                if (ol < tcnt) {
                    const int i = lo + tb + ol;
                    const int s = src[i], d = dst[i];
                    bb[j] = d >> 8;
                    rec[j] = ((unsigned)s << 8) | (unsigned)(d & 255);
                    rk[j] = atomicAdd(&sm.p.cnt[bb[j]], 1);
                } else bb[j] = -1;
            }
            __syncthreads();

            // 256-wide exclusive scan of cnt -> toff
            const int lane = tid & 63, wv = tid >> 6;
            const int v = sm.p.cnt[tid];
            int incl = v;
            #pragma unroll
            for (int s = 1; s < 64; s <<= 1) {
                const int t = __shfl_up(incl, s, 64);
                if (lane >= s) incl += t;
            }
            if (lane == 63) sm.p.wsum[wv] = incl;
            __syncthreads();
            if (tid == 0) {
                int a = 0;
                #pragma unroll
                for (int i = 0; i < 4; ++i) { const int t = sm.p.wsum[i]; sm.p.wsum[i] = a; a += t; }
            }
            __syncthreads();
            sm.p.toff[tid] = sm.p.wsum[wv] + incl - v;
            __syncthreads();

            // scatter into LDS in bucket order
            #pragma unroll
            for (int j = 0; j < 8; ++j) {
                if (bb[j] >= 0) {
                    const int p = sm.p.toff[bb[j]] + rk[j];
                    sm.p.sbuf[p] = rec[j];
                    sm.p.bp[p] = (unsigned char)bb[j];
                }
            }
            __syncthreads();

            // linear copy-out: consecutive lanes -> consecutive slab addrs
            for (int o = tid; o < tcnt; o += 256) {
                const int b = sm.p.bp[o];
                const int gpos = sm.p.gcur[b] + (o - sm.p.toff[b]);
                if (gpos < SLAB_CAP)
                    slab[((size_t)b * PB + pid) * SLAB_CAP + gpos] = sm.p.sbuf[o];
            }
            __syncthreads();
            sm.p.gcur[tid] += sm.p.cnt[tid];
            __syncthreads();
        }

        if (tid < NB) {
            const int c = min(sm.p.gcur[tid], SLAB_CAP);
            gcnt[tid * PB + pid] = c;
            atomicAdd(&ghist[tid], c);
        }
        return;
    }

    // ---- qkv role (MFMA, round-14 verbatim) ----
    const int qb = bx - bx / 13;         // dense id: skips all %13==12 slots
    const int node0 = qb * 16;

    for (int i = tid; i < 512; i += 256) {          // 512 float4 = 16 x 32
        const int r = i >> 5, c4 = (i & 31) * 4;
        *(float4*)&sm.xs[r][c4] = *(const float4*)&x[(size_t)(node0 + r) * F_IN + c4];
    }
    __syncthreads();

    const int w = tid >> 6;              // wave = col block (0..3)
    const int lane = tid & 63;
    const int row = lane & 15;
    const int kb = (lane >> 4) * 8;

    bf16x8 a[4];
    #pragma unroll
    for (int kg = 0; kg < 4; ++kg) {
        const float4 fa = *(const float4*)&sm.xs[row][kg * 32 + kb];
        const float4 fb = *(const float4*)&sm.xs[row][kg * 32 + kb + 4];
        a[kg][0] = (short)bf16_rne(fa.x); a[kg][1] = (short)bf16_rne(fa.y);
        a[kg][2] = (short)bf16_rne(fa.z); a[kg][3] = (short)bf16_rne(fa.w);
        a[kg][4] = (short)bf16_rne(fb.x); a[kg][5] = (short)bf16_rne(fb.y);
        a[kg][6] = (short)bf16_rne(fb.z); a[kg][7] = (short)bf16_rne(fb.w);
    }

    const bf16x8* Wp = (const bf16x8*)Wpk;
    f32x4 accQ = {0.f, 0.f, 0.f, 0.f};
    f32x4 accK = {0.f, 0.f, 0.f, 0.f};
    f32x4 accV = {0.f, 0.f, 0.f, 0.f};
    #pragma unroll
    for (int kg = 0; kg < 4; ++kg) {
        accQ = __builtin_amdgcn_mfma_f32_16x16x32_bf16(
            a[kg], Wp[((0 * 4 + w) * 4 + kg) * 64 + lane], accQ, 0, 0, 0);
        accK = __builtin_amdgcn_mfma_f32_16x16x32_bf16(
            a[kg], Wp[((1 * 4 + w) * 4 + kg) * 64 + lane], accK, 0, 0, 0);
        accV = __builtin_amdgcn_mfma_f32_16x16x32_bf16(
            a[kg], Wp[((2 * 4 + w) * 4 + kg) * 64 + lane], accV, 0, 0, 0);
    }

    const int crow0 = (lane >> 4) * 4;
    const int ccol = w * 16 + (lane & 15);
    #pragma unroll
    for (int r = 0; r < 4; ++r) {
        const int n = node0 + crow0 + r;
        Q[(size_t)n * HD + ccol] = accQ[r];
        KV[(size_t)n * HD + ccol] = pack_kv(accK[r], accV[r]);
    }
}

// ---------------------------------------------------------------------------
// bucket_csr (round-15 proven): one block per bucket; LDS deg-count -> scan
// -> off[] -> place into the bucket's contiguous esrc region.
// ---------------------------------------------------------------------------
__global__ void __launch_bounds__(256)
bucket_csr(const unsigned* __restrict__ slab,
           const int* __restrict__ gcnt,
           const int* __restrict__ ghist,
           int* __restrict__ off,
           int* __restrict__ esrc) {
    const int b = blockIdx.x;
    const int tid = threadIdx.x;
    __shared__ int hist_s[NB];
    __shared__ int deg[256], cursor[256];
    __shared__ int wsum[4];
    __shared__ int base_s;

    if (tid < NB) hist_s[tid] = ghist[tid];
    deg[tid] = 0;
    __syncthreads();
    if (tid == 0) {
        int s = 0;
        for (int i = 0; i < b; ++i) s += hist_s[i];
        base_s = s;
    }

    const int myc = gcnt[b * PB + tid];
    const unsigned* myslab = slab + ((size_t)b * PB + tid) * SLAB_CAP;

    for (int c = 0; c < myc; ++c) atomicAdd(&deg[(int)(myslab[c] & 255u)], 1);
    __syncthreads();

    const int lane = tid & 63, wv = tid >> 6;
    const int v = deg[tid];
    int incl = v;
    #pragma unroll
    for (int s = 1; s < 64; s <<= 1) {
        const int t = __shfl_up(incl, s, 64);
        if (lane >= s) incl += t;
    }
    if (lane == 63) wsum[wv] = incl;
    __syncthreads();
    if (tid == 0) {
        int a = 0;
        #pragma unroll
        for (int i = 0; i < 4; ++i) { const int t = wsum[i]; wsum[i] = a; a += t; }
    }
    __syncthreads();
    const int ex = wsum[wv] + incl - v;
    cursor[tid] = ex;

    const int base = base_s;
    const int n = b * 256 + tid;
    if (n <= N_NODES) off[n] = base + ex;
    __syncthreads();

    for (int c = 0; c < myc; ++c) {
        const unsigned r = myslab[c];
        const int pos = atomicAdd(&cursor[(int)(r & 255u)], 1);
        esrc[base + pos] = (int)(r >> 8);
    }
}

// ---------------------------------------------------------------------------
// Gather (round-15 proven CSR form).
// ---------------------------------------------------------------------------
__global__ void gather_csr(const int* __restrict__ off,
                           const int* __restrict__ esrc,
                           const float* __restrict__ Q,
                           const unsigned* __restrict__ KV,
                           float* __restrict__ out) {
    const int n = blockIdx.x * 4 + (threadIdx.x >> 6);
    if (n >= N_NODES) return;
    const int lane = threadIdx.x & 63;
    const int t = lane >> 2;
    const int h = lane & 3;
    const int beg = off[n];
    const int end = off[n + 1];

    float qv[16];
    {
        const float4* qp = (const float4*)(Q + (size_t)n * HD + h * DPH);
        #pragma unroll
        for (int j = 0; j < 4; ++j) {
            const float4 f = qp[j];
            qv[4 * j + 0] = f.x; qv[4 * j + 1] = f.y;
            qv[4 * j + 2] = f.z; qv[4 * j + 3] = f.w;
        }
    }

    float acc[16];
    #pragma unroll
    for (int j = 0; j < 16; ++j) acc[j] = 0.f;
    float zacc = 0.f;

    for (int base = beg; base < end; base += 16) {
        const int idx = base + t;
        const bool valid = idx < end;
        const int s = esrc[valid ? idx : end - 1];
        const uint4* kp = (const uint4*)(KV + (size_t)s * HD + h * DPH);
        const uint4 w0 = kp[0], w1 = kp[1], w2 = kp[2], w3 = kp[3];
        const unsigned kw[16] = {w0.x, w0.y, w0.z, w0.w,
                                 w1.x, w1.y, w1.z, w1.w,
                                 w2.x, w2.y, w2.z, w2.w,
                                 w3.x, w3.y, w3.z, w3.w};
        float p = 0.f;
        #pragma unroll
        for (int j = 0; j < 16; ++j)
            p = fmaf(__uint_as_float(kw[j] << 16), qv[j], p);
        p = fminf(fmaxf(p * 0.25f, -5.f), 5.f);
        float sc = __expf(p);
        sc = valid ? sc : 0.f;
        #pragma unroll
        for (int j = 0; j < 16; ++j)
            acc[j] = fmaf(sc, __uint_as_float(kw[j] & 0xFFFF0000u), acc[j]);
        zacc += sc;
    }

    // Reduce-scatter over t bits (masks 32,16,8,4 -> element bits 3,2,1,0).
    {
        const bool b = (lane & 32) != 0;
        float send[8], keep[8];
        #pragma unroll
        for (int j = 0; j < 8; ++j) {
            send[j] = b ? acc[j] : acc[j + 8];
            keep[j] = b ? acc[j + 8] : acc[j];
        }
        #pragma unroll
        for (int j = 0; j < 8; ++j) acc[j] = keep[j] + __shfl_xor(send[j], 32, 64);
    }
    {
        const bool b = (lane & 16) != 0;
        float send[4], keep[4];
        #pragma unroll
        for (int j = 0; j < 4; ++j) {
            send[j] = b ? acc[j] : acc[j + 4];
            keep[j] = b ? acc[j + 4] : acc[j];
        }
        #pragma unroll
        for (int j = 0; j < 4; ++j) acc[j] = keep[j] + __shfl_xor(send[j], 16, 64);
    }
    {
        const bool b = (lane & 8) != 0;
        float send[2], keep[2];
        #pragma unroll
        for (int j = 0; j < 2; ++j) {
            send[j] = b ? acc[j] : acc[j + 2];
            keep[j] = b ? acc[j + 2] : acc[j];
        }
        #pragma unroll
        for (int j = 0; j < 2; ++j) acc[j] = keep[j] + __shfl_xor(send[j], 8, 64);
    }
    {
        const bool b = (lane & 4) != 0;
        const float send = b ? acc[0] : acc[1];
        const float keep = b ? acc[1] : acc[0];
        acc[0] = keep + __shfl_xor(send, 4, 64);
    }

    zacc += __shfl_xor(zacc, 4, 64);
    zacc += __shfl_xor(zacc, 8, 64);
    zacc += __shfl_xor(zacc, 16, 64);
    zacc += __shfl_xor(zacc, 32, 64);

    out[(size_t)n * HD + h * DPH + t] = acc[0] / (zacc + 1e-6f);
}

extern "C" void kernel_launch(void* const* d_in, const int* in_sizes, int n_in,
                              void* d_out, int out_size, void* d_ws, size_t ws_size,
                              hipStream_t stream) {
    const float* x   = (const float*)d_in[0];
    const int*   src = (const int*)d_in[1];
    const int*   dst = (const int*)d_in[2];
    const float* Wq  = (const float*)d_in[3];
    const float* Wk  = (const float*)d_in[4];
    const float* Wv  = (const float*)d_in[5];
    float* out = (float*)d_out;

    float*    Q     = (float*)d_ws;                            // 12.8 MB
    unsigned* KV    = (unsigned*)(Q + (size_t)N_NODES * HD);   // 12.8 MB
    uint4*    Wpk   = (uint4*)(KV + (size_t)N_NODES * HD);     // 48 KB
    unsigned* slab  = (unsigned*)(Wpk + 12 * 4 * 64);          // 14.45 MB
    int*      gcnt  = (int*)(slab + (size_t)NB * PB * SLAB_CAP); // 200 KB
    int*      ghist = gcnt + NB * PB;                          // 784 B
    int*      off   = ghist + NB;                              // 200 KB
    int*      esrc  = off + (N_NODES + 1);                     // 6.4 MB

    hipMemsetAsync(ghist, 0, NB * sizeof(int), stream);

    repack_w<<<12, 256, 0, stream>>>(Wq, Wk, Wv, Wpk);
    qkv_and_partition<<<FUSED_TOTAL, 256, 0, stream>>>(x, Wpk, src, dst,
                                                       Q, KV, slab, gcnt, ghist);
    bucket_csr<<<NB, 256, 0, stream>>>(slab, gcnt, ghist, off, esrc);
    gather_csr<<<(N_NODES + 3) / 4, 256, 0, stream>>>(off, esrc, Q, KV, out);
}